// Round 9
// baseline (143.235 us; speedup 1.0000x reference)
//
#include <hip/hip_runtime.h>
#include <math.h>

#define BLOCK 256                 // 4 waves/block
#define GRID  1024                // 4096 waves total
#define NWAVES (GRID * (BLOCK/64))
#define SELEM 256                 // elements per wave-stage

// theta^2 for rel = qinv(a) * idd.  Hastings acos approx, err ~6.8e-5 rad.
__device__ __forceinline__ float theta_sq(float4 qa, float4 qb) {
    float w1 = qa.x, x1 = -qa.y, y1 = -qa.z, z1 = -qa.w;
    float w2 = qb.x, x2 = qb.y,  y2 = qb.z,  z2 = qb.w;
    float w  = w1*w2 - (x1*x2 + y1*y2 + z1*z2);
    float vx = w1*x2 + w2*x1 + (y1*z2 - z1*y2);
    float vy = w1*y2 + w2*y1 + (z1*x2 - x1*z2);
    float vz = w1*z2 + w2*z1 + (x1*y2 - y1*x2);
    float nv2 = vx*vx + vy*vy + vz*vz;
    float nv  = sqrtf(nv2);
    if (nv < 1e-6f) {                    // reference small-angle branch
        float s = 2.0f / w;
        return nv2 * s * s;
    }
    float rn = rsqrtf(w*w + nv2);
    float c  = w * rn;                   // cos(theta/2) in [-1,1]
    float ac = fabsf(c);
    float p  = ((-0.0187293f*ac + 0.0742610f)*ac - 0.2121144f)*ac + 1.5707288f;
    float r  = sqrtf(fmaxf(1.0f - ac, 0.0f)) * p;
    float acosc = (c >= 0.0f) ? r : (3.14159265358979f - r);
    float theta = 2.0f * acosc;
    return theta * theta;
}

// Hybrid read-path probe: stream `a` via LDS-DMA (global_load_lds),
// stream `idd` via vector loads (VGPR return) — both counted by vmcnt,
// issued back-to-back so both queues are saturated simultaneously.
__global__ __launch_bounds__(BLOCK) void geo_loss_kernel(
        const float4* __restrict__ a,
        const float4* __restrict__ idd,
        float* __restrict__ partials, int n) {
    __shared__ float4 sA[4][SELEM];      // 16 KB: one 4 KB slot per wave
    const int tid  = threadIdx.x;
    const int lane = tid & 63;
    const int wid  = tid >> 6;
    const int gwave = blockIdx.x * (BLOCK / 64) + wid;
    const int nstages = n / SELEM;       // 15625 for N=4M (exact)
    float acc = 0.0f;

    for (int s = gwave; s < nstages; s += NWAVES) {
        const int ebase = s * SELEM;
        // path 1: a -> LDS via DMA (4 x 1KB wave-instructions)
        #pragma unroll
        for (int k = 0; k < 4; k++) {
            __builtin_amdgcn_global_load_lds(
                (const __attribute__((address_space(1))) void*)(a + ebase + k * 64 + lane),
                (__attribute__((address_space(3))) void*)(&sA[wid][k * 64]),
                16, 0, 0);
        }
        // path 2: idd -> VGPRs via vector loads (4 x dwordx4 per lane)
        float4 qb[4];
        #pragma unroll
        for (int k = 0; k < 4; k++) qb[k] = idd[ebase + k * 64 + lane];

        __builtin_amdgcn_s_waitcnt(0x0F70);   // vmcnt(0); exp=7, lgkm=15
        #pragma unroll
        for (int k = 0; k < 4; k++)
            acc += theta_sq(sA[wid][k * 64 + lane], qb[k]);
    }

    // generic tail (empty for N=4M since 4e6 % 256 == 0)
    for (int idx = nstages * SELEM + blockIdx.x * BLOCK + tid; idx < n;
         idx += GRID * BLOCK)
        acc += theta_sq(a[idx], idd[idx]);

    // wave-64 reduction
    #pragma unroll
    for (int off = 32; off > 0; off >>= 1)
        acc += __shfl_down(acc, off, 64);
    __shared__ float smem[BLOCK / 64];
    if (lane == 0) smem[wid] = acc;
    __syncthreads();
    if (tid == 0)
        partials[blockIdx.x] = smem[0] + smem[1] + smem[2] + smem[3];
}

__global__ __launch_bounds__(256) void finalize_kernel(
        const float* __restrict__ partials,
        float* __restrict__ out, int nparts) {
    float acc = 0.0f;
    for (int i = threadIdx.x; i < nparts; i += 256)
        acc += partials[i];
    #pragma unroll
    for (int off = 32; off > 0; off >>= 1)
        acc += __shfl_down(acc, off, 64);
    __shared__ float smem[4];
    int lane = threadIdx.x & 63;
    int wid  = threadIdx.x >> 6;
    if (lane == 0) smem[wid] = acc;
    __syncthreads();
    if (threadIdx.x == 0)
        out[0] = sqrtf(smem[0] + smem[1] + smem[2] + smem[3]);
}

extern "C" void kernel_launch(void* const* d_in, const int* in_sizes, int n_in,
                              void* d_out, int out_size, void* d_ws, size_t ws_size,
                              hipStream_t stream) {
    const float4* a   = (const float4*)d_in[0];
    const float4* idd = (const float4*)d_in[1];
    int n = in_sizes[0] / 4;             // 4,000,000 quaternions
    float* ws = (float*)d_ws;

    geo_loss_kernel<<<GRID, BLOCK, 0, stream>>>(a, idd, ws, n);
    finalize_kernel<<<1, 256, 0, stream>>>(ws, (float*)d_out, GRID);
}